// Round 4
// baseline (418.211 us; speedup 1.0000x reference)
//
#include <hip/hip_runtime.h>

// SpectralRewiringLayer. Factorized: h1 = relu(u[src] + v[dst]),
//   u[n] = W1[0:64]^T emb[n] + b1 + fied[n]*W1[128]
//   v[n] = W1[64:128]^T emb[n] + fied[n]*W1[129]
// fp16 u,v. K1: transposed MFMA GEMM (unchanged).
//
// R7: model rate=M/L, M~64 lines/CU. Levers: line count (u-from-LDS,
// proven R5) and v latency (needs per-XCD L2 residency). R6's ticket/
// phase machinery serialized everything (249us). Now STATIC pinning:
// grid 2048, block b = bucket (src-slice b>>3, dst-slice b&7); dispatcher
// round-robin => b&7 ~ physical XCD => v-slice (1.6MB) stays in its XCD's
// L2 with ZERO coordination. Sort collapsed to ONE single-pass kernel:
// atomic-append into over-allocated buckets (CAP=mean+8sigma, overflow
// spills to list; cleanup kernel is correctness-only). Staging
// de-serialized: 13-deep batched loads, then guarded LDS writes.

#define HD 64
#define SRC_B 256
#define DST_B 8
#define NBK (SRC_B * DST_B)   // 2048 buckets
#define CAP 1216              // bucket capacity (mean 977 + ~8 sigma)
#define OVF_CAP 65536

typedef __attribute__((ext_vector_type(8))) _Float16 half8;
typedef __attribute__((ext_vector_type(4))) _Float16 half4;
typedef __attribute__((ext_vector_type(8))) short  short8;
typedef __attribute__((ext_vector_type(8))) float  float8;
typedef __attribute__((ext_vector_type(4))) float  f32x4;

__device__ __forceinline__ half8 relu_h8(half8 x) {
    short8 b = __builtin_bit_cast(short8, x);
    short8 m = b >> 15;
    b = b & ~m;
    return __builtin_bit_cast(half8, b);
}

// ---------------- K1: u,v precompute, transposed MFMA GEMM ----------------
__global__ __launch_bounds__(256) void precompute_uv(
    const float* __restrict__ emb, const float* __restrict__ fied,
    const float* __restrict__ W1, const float* __restrict__ b1,
    _Float16* __restrict__ u, _Float16* __restrict__ v,
    int n_nodes, int ntiles)
{
    const int lane = threadIdx.x & 63;
    const int q = lane >> 4;
    const int c = lane & 15;
    const int wid = blockIdx.x * (blockDim.x >> 6) + (threadIdx.x >> 6);
    const int nw  = gridDim.x * (blockDim.x >> 6);

    half8 Au[4][2], Av[4][2];
    #pragma unroll
    for (int t = 0; t < 4; ++t)
        #pragma unroll
        for (int ks = 0; ks < 2; ++ks)
            #pragma unroll
            for (int j = 0; j < 8; ++j) {
                int k = ks * 32 + q * 8 + j;
                Au[t][ks][j] = (_Float16)W1[k * HD + t * 16 + c];
                Av[t][ks][j] = (_Float16)W1[(64 + k) * HD + t * 16 + c];
            }
    f32x4 b1q[4], wsq[4], wdq[4];
    #pragma unroll
    for (int t = 0; t < 4; ++t) {
        b1q[t] = *(const f32x4*)(b1 + t * 16 + q * 4);
        wsq[t] = *(const f32x4*)(W1 + 128 * HD + t * 16 + q * 4);
        wdq[t] = *(const f32x4*)(W1 + 129 * HD + t * 16 + q * 4);
    }

    for (int tile = wid; tile < ntiles; tile += nw) {
        const int n0 = tile * 16;
        const int n  = n0 + c;
        int na = n; if (na >= n_nodes) na = n_nodes - 1;
        const float* rp = emb + (size_t)na * HD + q * 8;
        float8 a0 = *(const float8*)rp;
        float8 a1 = *(const float8*)(rp + 32);
        half8 B0 = __builtin_convertvector(a0, half8);
        half8 B1 = __builtin_convertvector(a1, half8);

        f32x4 aU[4] = {}, aV[4] = {};
        #pragma unroll
        for (int t = 0; t < 4; ++t) {
            aU[t] = __builtin_amdgcn_mfma_f32_16x16x32_f16(Au[t][0], B0, aU[t], 0, 0, 0);
            aU[t] = __builtin_amdgcn_mfma_f32_16x16x32_f16(Au[t][1], B1, aU[t], 0, 0, 0);
            aV[t] = __builtin_amdgcn_mfma_f32_16x16x32_f16(Av[t][0], B0, aV[t], 0, 0, 0);
            aV[t] = __builtin_amdgcn_mfma_f32_16x16x32_f16(Av[t][1], B1, aV[t], 0, 0, 0);
        }

        const float fv = fied[na];
        const bool ok = (n < n_nodes);
        #pragma unroll
        for (int t = 0; t < 4; ++t) {
            half4 hu, hv;
            #pragma unroll
            for (int r = 0; r < 4; ++r) {
                hu[r] = (_Float16)(aU[t][r] + b1q[t][r] + fv * wsq[t][r]);
                hv[r] = (_Float16)(aV[t][r] + fv * wdq[t][r]);
            }
            if (ok) {
                *(half4*)(u + (size_t)n * HD + t * 16 + q * 4) = hu;
                *(half4*)(v + (size_t)n * HD + t * 16 + q * 4) = hv;
            }
        }
    }
}

// ---------------- fallback K2 (ws too small): per-edge MLP ----------------
__global__ __launch_bounds__(256) void edge_mlp(
    const _Float16* __restrict__ u, const _Float16* __restrict__ v,
    const int* __restrict__ src, const int* __restrict__ dst,
    const float* __restrict__ W2, const float* __restrict__ b2,
    const float* __restrict__ W3, const float* __restrict__ b3,
    float* __restrict__ out, int E, int ntiles)
{
    const int lane = threadIdx.x & 63;
    const int q = lane >> 4;
    const int c = lane & 15;
    const int wid = blockIdx.x * (blockDim.x >> 6) + (threadIdx.x >> 6);
    const int nw  = gridDim.x * (blockDim.x >> 6);

    half8 Af[4][2];
    #pragma unroll
    for (int t = 0; t < 4; ++t)
        #pragma unroll
        for (int ks = 0; ks < 2; ++ks)
            #pragma unroll
            for (int j = 0; j < 8; ++j) {
                int k = ks * 32 + q * 8 + j;
                Af[t][ks][j] = (_Float16)W2[k * HD + t * 16 + c];
            }
    f32x4 b2q[4], w3q[4];
    #pragma unroll
    for (int t = 0; t < 4; ++t) {
        b2q[t] = *(const f32x4*)(b2 + t * 16 + q * 4);
        w3q[t] = *(const f32x4*)(W3 + t * 16 + q * 4);
    }
    const float b3v = b3[0];

    const int stride = nw * 2;
    const int base0  = wid * 2;

    auto eid = [&](int tile) {
        int t = tile; if (t >= ntiles) t = ntiles - 1;
        int e = t * 16 + c; if (e >= E) e = E - 1;
        return e;
    };
    auto issue = [&](int s, int d, half8& Ua, half8& Ub, half8& Va, half8& Vb) {
        const half8* up = (const half8*)(u + (unsigned)s * HD + q * 8);
        const half8* vp = (const half8*)(v + (unsigned)d * HD + q * 8);
        Ua = up[0]; Ub = up[4]; Va = vp[0]; Vb = vp[4];
    };
    auto compute_store = [&](int tile, half8 Ua, half8 Ub, half8 Va, half8 Vb) {
        half8 B0 = relu_h8(Ua + Va);
        half8 B1 = relu_h8(Ub + Vb);
        f32x4 acc[4];
        #pragma unroll
        for (int t = 0; t < 4; ++t) acc[t] = b2q[t];
        #pragma unroll
        for (int t = 0; t < 4; ++t) {
            acc[t] = __builtin_amdgcn_mfma_f32_16x16x32_f16(Af[t][0], B0, acc[t], 0, 0, 0);
            acc[t] = __builtin_amdgcn_mfma_f32_16x16x32_f16(Af[t][1], B1, acc[t], 0, 0, 0);
        }
        float p = 0.f;
        #pragma unroll
        for (int t = 0; t < 4; ++t)
            #pragma unroll
            for (int r = 0; r < 4; ++r)
                p = fmaf(fmaxf(acc[t][r], 0.f), w3q[t][r], p);
        p += __shfl_xor(p, 16, 64);
        p += __shfl_xor(p, 32, 64);
        if (q == 0) {
            int e = tile * 16 + c;
            if (e < E) out[e] = p + b3v;
        }
    };

    if (base0 >= ntiles) return;

    int e0 = eid(base0), e1 = eid(base0 + 1);
    int s0 = src[e0], d0 = dst[e0];
    int s1 = src[e1], d1 = dst[e1];
    half8 U0a, U0b, V0a, V0b, U1a, U1b, V1a, V1b;
    issue(s0, d0, U0a, U0b, V0a, V0b);
    issue(s1, d1, U1a, U1b, V1a, V1b);
    int e2 = eid(base0 + stride), e3 = eid(base0 + stride + 1);
    int sc0 = src[e2], dc0 = dst[e2];
    int sc1 = src[e3], dc1 = dst[e3];

    for (int base = base0; base < ntiles; base += stride) {
        const int f0 = eid(base + 2 * stride), f1 = eid(base + 2 * stride + 1);
        const int sn0 = src[f0], dn0 = dst[f0];
        const int sn1 = src[f1], dn1 = dst[f1];

        compute_store(base, U0a, U0b, V0a, V0b);
        issue(sc0, dc0, U0a, U0b, V0a, V0b);

        compute_store(base + 1, U1a, U1b, V1a, V1b);
        issue(sc1, dc1, U1a, U1b, V1a, V1b);

        sc0 = sn0; dc0 = dn0; sc1 = sn1; dc1 = dn1;
    }
}

// ---------------- zero pass (bucket counters + overflow counter) ----------
__global__ __launch_bounds__(256) void zero_k(unsigned* __restrict__ p, int n)
{
    const int i = blockIdx.x * 256 + threadIdx.x;
    if (i < n) p[i] = 0u;
}

// ---------------- single-pass bucket append (NO hist/scan/scat) -----------
// bucket(e) = src_slice(256) * 8 + dst_slice(8). Over-allocated CAP slots
// per bucket; statistically impossible overflow spills to ovf list.
__global__ __launch_bounds__(256) void append_k(
    const int* __restrict__ src, const int* __restrict__ dst,
    unsigned long long* __restrict__ recs, unsigned* __restrict__ cnt,
    unsigned* __restrict__ ovfc, unsigned long long* __restrict__ ovf,
    int E, unsigned mulSL, unsigned mul8)
{
    const int step = gridDim.x * 256;
    for (int i = blockIdx.x * 256 + threadIdx.x; i < E; i += step) {
        const unsigned s = (unsigned)src[i], d = (unsigned)dst[i];
        const unsigned bk = __umulhi(s, mulSL) * 8u + __umulhi(d, mul8);
        const unsigned long long rec = (unsigned long long)s
                                     | ((unsigned long long)d << 17)
                                     | ((unsigned long long)(unsigned)i << 34);
        const unsigned slot = atomicAdd(&cnt[bk], 1u);
        if (slot < (unsigned)CAP) {
            recs[(size_t)bk * CAP + slot] = rec;
        } else {
            const unsigned o = atomicAdd(ovfc, 1u);
            if (o < (unsigned)OVF_CAP) ovf[o] = rec;
        }
    }
}

// ---------------- K2: statically XCD-pinned per-bucket MLP ----------------
// Block b <-> bucket (src-slice b>>3, dst-slice b&7). Dispatcher
// round-robins blocks over the 8 XCDs, so b&7 ~ physical XCD: v-slice
// (1.6MB) stays resident in its own XCD's 4MB L2 for the whole kernel.
// u-slice staged once into LDS (13-deep BATCHED loads, then guarded
// swizzled writes — no serial load->write dependence chain).
__global__ __launch_bounds__(256) void edge_mlp_p(
    const _Float16* __restrict__ u, const _Float16* __restrict__ v,
    const unsigned long long* __restrict__ recs,
    const unsigned* __restrict__ cntp,
    const float* __restrict__ W2, const float* __restrict__ b2,
    const float* __restrict__ W3, const float* __restrict__ b3,
    float* __restrict__ out, int n_nodes, int SL)
{
    extern __shared__ _Float16 us[];
    const int tid  = threadIdx.x;
    const int lane = tid & 63;
    const int q = lane >> 4;
    const int c = lane & 15;
    const int bk = blockIdx.x;
    const int sb = bk >> 3;

    // ---- stage u-slice: 13 batched independent loads, then LDS writes ----
    const int node0 = sb * SL;
    int nrows = n_nodes - node0; if (nrows > SL) nrows = SL;
    const int total = nrows * 8;            // <= SL*8 <= 3328 = 13*256
    half8 stg[13];
    int   srow[13], schk[13];
    #pragma unroll
    for (int k = 0; k < 13; ++k) {
        int i = tid + k * 256;
        int ii = (i < total) ? i : (total - 1);
        srow[k] = ii >> 3; schk[k] = ii & 7;
        stg[k] = *(const half8*)(u + (size_t)(node0 + srow[k]) * HD + schk[k] * 8);
    }
    #pragma unroll
    for (int k = 0; k < 13; ++k) {
        int i = tid + k * 256;
        if (i < total)
            *(half8*)(us + srow[k] * HD + ((schk[k] ^ (srow[k] & 7)) * 8)) = stg[k];
    }

    half8 Af[4][2];
    #pragma unroll
    for (int t = 0; t < 4; ++t)
        #pragma unroll
        for (int ks = 0; ks < 2; ++ks)
            #pragma unroll
            for (int j = 0; j < 8; ++j) {
                int k = ks * 32 + q * 8 + j;
                Af[t][ks][j] = (_Float16)W2[k * HD + t * 16 + c];
            }
    f32x4 b2q[4], w3q[4];
    #pragma unroll
    for (int t = 0; t < 4; ++t) {
        b2q[t] = *(const f32x4*)(b2 + t * 16 + q * 4);
        w3q[t] = *(const f32x4*)(W3 + t * 16 + q * 4);
    }
    const float b3v = b3[0];

    __syncthreads();

    unsigned cnt = cntp[bk];
    if (cnt > (unsigned)CAP) cnt = (unsigned)CAP;   // excess lives in ovf
    if (cnt == 0) return;
    const int ntiles = (int)((cnt + 15u) >> 4);
    const size_t rbase = (size_t)bk * CAP;

    const int w = tid >> 6;                 // 0..3
    const int stride = 8;                   // 4 waves x depth-2
    const int base0  = w * 2;
    if (base0 >= ntiles) return;

    auto ridx = [&](int tile) -> size_t {
        int t = tile; if (t >= ntiles) t = ntiles - 1;
        unsigned r = (unsigned)t * 16u + (unsigned)c;
        if (r >= cnt) r = cnt - 1u;
        return rbase + r;
    };
    auto issueV = [&](unsigned d, half8& Va, half8& Vb) {
        const half8* vp = (const half8*)(v + (unsigned)d * HD + q * 8);
        Va = vp[0]; Vb = vp[4];
    };
    auto compute_store = [&](int tile, unsigned eid, unsigned s,
                             half8 Va, half8 Vb) {
        const int sl = (int)s - node0;
        const half8 Ua = *(const half8*)(us + sl * HD + ((q ^ (sl & 7)) * 8));
        const half8 Ub = *(const half8*)(us + sl * HD + (((q + 4) ^ (sl & 7)) * 8));
        half8 B0 = relu_h8(Ua + Va);
        half8 B1 = relu_h8(Ub + Vb);
        f32x4 acc[4];
        #pragma unroll
        for (int t = 0; t < 4; ++t) acc[t] = b2q[t];   // b2 via MFMA C-in
        #pragma unroll
        for (int t = 0; t < 4; ++t) {
            acc[t] = __builtin_amdgcn_mfma_f32_16x16x32_f16(Af[t][0], B0, acc[t], 0, 0, 0);
            acc[t] = __builtin_amdgcn_mfma_f32_16x16x32_f16(Af[t][1], B1, acc[t], 0, 0, 0);
        }
        float p = 0.f;
        #pragma unroll
        for (int t = 0; t < 4; ++t)
            #pragma unroll
            for (int r = 0; r < 4; ++r)
                p = fmaf(fmaxf(acc[t][r], 0.f), w3q[t][r], p);
        p += __shfl_xor(p, 16, 64);
        p += __shfl_xor(p, 32, 64);
        if (q == 0 && ((unsigned)tile * 16u + (unsigned)c) < cnt)
            out[eid] = p + b3v;
    };

    // ---- prologue: recs prefetched one iteration ahead ----
    unsigned long long r0 = recs[ridx(base0)];
    unsigned long long r1 = recs[ridx(base0 + 1)];
    unsigned s0 = (unsigned)r0 & 0x1FFFFu;
    unsigned s1 = (unsigned)r1 & 0x1FFFFu;
    unsigned e0 = (unsigned)(r0 >> 34), e1 = (unsigned)(r1 >> 34);
    half8 V0a, V0b, V1a, V1b;
    issueV((unsigned)(r0 >> 17) & 0x1FFFFu, V0a, V0b);
    issueV((unsigned)(r1 >> 17) & 0x1FFFFu, V1a, V1b);
    unsigned long long rc0 = recs[ridx(base0 + stride)];
    unsigned long long rc1 = recs[ridx(base0 + stride + 1)];

    for (int bse = base0; bse < ntiles; bse += stride) {
        const unsigned long long rn0 = recs[ridx(bse + 2 * stride)];
        const unsigned long long rn1 = recs[ridx(bse + 2 * stride + 1)];

        compute_store(bse, e0, s0, V0a, V0b);
        s0 = (unsigned)rc0 & 0x1FFFFu;
        e0 = (unsigned)(rc0 >> 34);
        issueV((unsigned)(rc0 >> 17) & 0x1FFFFu, V0a, V0b);

        compute_store(bse + 1, e1, s1, V1a, V1b);
        s1 = (unsigned)rc1 & 0x1FFFFu;
        e1 = (unsigned)(rc1 >> 34);
        issueV((unsigned)(rc1 >> 17) & 0x1FFFFu, V1a, V1b);

        rc0 = rn0; rc1 = rn1;
    }
}

// ---------------- overflow cleanup (expected 0 edges; correctness) --------
__global__ __launch_bounds__(256) void ovf_k(
    const _Float16* __restrict__ u, const _Float16* __restrict__ v,
    const unsigned long long* __restrict__ ovf,
    const unsigned* __restrict__ ovfc,
    const float* __restrict__ W2, const float* __restrict__ b2,
    const float* __restrict__ W3, const float* __restrict__ b3,
    float* __restrict__ out)
{
    int n = (int)*ovfc;
    if (n > OVF_CAP) n = OVF_CAP;
    if (n <= 0) return;
    const int lane = threadIdx.x & 63;
    const int q = lane >> 4;
    const int c = lane & 15;
    const int wid = blockIdx.x * (blockDim.x >> 6) + (threadIdx.x >> 6);
    const int nw  = gridDim.x * (blockDim.x >> 6);

    half8 Af[4][2];
    #pragma unroll
    for (int t = 0; t < 4; ++t)
        #pragma unroll
        for (int ks = 0; ks < 2; ++ks)
            #pragma unroll
            for (int j = 0; j < 8; ++j) {
                int k = ks * 32 + q * 8 + j;
                Af[t][ks][j] = (_Float16)W2[k * HD + t * 16 + c];
            }
    f32x4 b2q[4], w3q[4];
    #pragma unroll
    for (int t = 0; t < 4; ++t) {
        b2q[t] = *(const f32x4*)(b2 + t * 16 + q * 4);
        w3q[t] = *(const f32x4*)(W3 + t * 16 + q * 4);
    }
    const float b3v = b3[0];

    const int ntiles = (n + 15) / 16;
    for (int tile = wid; tile < ntiles; tile += nw) {
        int idx = tile * 16 + c; if (idx >= n) idx = n - 1;
        const unsigned long long rec = ovf[idx];
        const unsigned s = (unsigned)rec & 0x1FFFFu;
        const unsigned d = (unsigned)(rec >> 17) & 0x1FFFFu;
        const unsigned e = (unsigned)(rec >> 34);
        const half8* up = (const half8*)(u + (size_t)s * HD + q * 8);
        const half8* vp = (const half8*)(v + (size_t)d * HD + q * 8);
        half8 B0 = relu_h8(up[0] + vp[0]);
        half8 B1 = relu_h8(up[4] + vp[4]);
        f32x4 acc[4];
        #pragma unroll
        for (int t = 0; t < 4; ++t) acc[t] = b2q[t];
        #pragma unroll
        for (int t = 0; t < 4; ++t) {
            acc[t] = __builtin_amdgcn_mfma_f32_16x16x32_f16(Af[t][0], B0, acc[t], 0, 0, 0);
            acc[t] = __builtin_amdgcn_mfma_f32_16x16x32_f16(Af[t][1], B1, acc[t], 0, 0, 0);
        }
        float p = 0.f;
        #pragma unroll
        for (int t = 0; t < 4; ++t)
            #pragma unroll
            for (int r = 0; r < 4; ++r)
                p = fmaf(fmaxf(acc[t][r], 0.f), w3q[t][r], p);
        p += __shfl_xor(p, 16, 64);
        p += __shfl_xor(p, 32, 64);
        if (q == 0 && tile * 16 + c < n) out[e] = p + b3v;
    }
}

extern "C" void kernel_launch(void* const* d_in, const int* in_sizes, int n_in,
                              void* d_out, int out_size, void* d_ws, size_t ws_size,
                              hipStream_t stream) {
    const float* emb  = (const float*)d_in[0];
    const float* fied = (const float*)d_in[1];
    const float* W1   = (const float*)d_in[2];
    const float* b1   = (const float*)d_in[3];
    const float* W2   = (const float*)d_in[4];
    const float* b2   = (const float*)d_in[5];
    const float* W3   = (const float*)d_in[6];
    const float* b3   = (const float*)d_in[7];
    const int*   eidx = (const int*)d_in[8];

    const int n_nodes = in_sizes[1];
    const int E       = in_sizes[8] / 2;
    const int* srcp = eidx;
    const int* dstp = eidx + E;

    _Float16* u = (_Float16*)d_ws;                 // n_nodes*64 fp16
    _Float16* v = u + (size_t)n_nodes * HD;        // n_nodes*64 fp16
    const size_t uv_bytes = (size_t)n_nodes * HD * 2 * sizeof(_Float16);

    const int ntilesN = (n_nodes + 15) / 16;

    // workspace layout for bucketed path
    const size_t recs_off = uv_bytes;
    const size_t cnt_off  = recs_off + (size_t)NBK * CAP * 8;
    const size_t ovfc_off = cnt_off + (size_t)NBK * 4;
    const size_t ovf_off  = ovfc_off + 64;
    const size_t need     = ovf_off + (size_t)OVF_CAP * 8;

    const int SL = (n_nodes + SRC_B - 1) / SRC_B;       // fine slice size
    const size_t lds_bytes = (size_t)SL * HD * sizeof(_Float16);

    const bool can_bucket = (ws_size >= need) &&
                            (n_nodes <= 106496) && (n_nodes >= 4096) &&
                            (SL <= 416) && (lds_bytes <= 53248) &&
                            ((long long)E <= (1LL << 21));

    if (can_bucket) {
        unsigned long long* recs = (unsigned long long*)((char*)d_ws + recs_off);
        unsigned* cnt  = (unsigned*)((char*)d_ws + cnt_off);
        unsigned* ovfc = (unsigned*)((char*)d_ws + ovfc_off);
        unsigned long long* ovf = (unsigned long long*)((char*)d_ws + ovf_off);
        // floor(s/SL) = umulhi(s, mulSL) exact for s<2^17, SL<2^15
        const unsigned mulSL = (unsigned)(((1ULL << 32) + (unsigned)SL - 1) / (unsigned)SL);
        const unsigned mul8  = (unsigned)((8ULL << 32) / (unsigned long long)n_nodes);

        // zero cnt[NBK] + ovfc (contiguous region, NBK+16 words)
        zero_k<<<(NBK + 16 + 255) / 256, 256, 0, stream>>>(cnt, NBK + 16);
        append_k<<<1024, 256, 0, stream>>>(srcp, dstp, recs, cnt, ovfc, ovf,
                                           E, mulSL, mul8);
        precompute_uv<<<1024, 256, 0, stream>>>(emb, fied, W1, b1, u, v,
                                                n_nodes, ntilesN);
        edge_mlp_p<<<NBK, 256, lds_bytes, stream>>>(
            u, v, recs, cnt, W2, b2, W3, b3, (float*)d_out, n_nodes, SL);
        ovf_k<<<64, 256, 0, stream>>>(u, v, ovf, ovfc, W2, b2, W3, b3,
                                      (float*)d_out);
    } else {
        precompute_uv<<<1024, 256, 0, stream>>>(emb, fied, W1, b1, u, v,
                                                n_nodes, ntilesN);
        const int ntilesE = (E + 15) / 16;
        edge_mlp<<<2048, 256, 0, stream>>>(u, v, srcp, dstp, W2, b2, W3, b3,
                                           (float*)d_out, E, ntilesE);
    }
}

// Round 5
// 178.375 us; speedup vs baseline: 2.3446x; 2.3446x over previous
//
#include <hip/hip_runtime.h>

// SpectralRewiringLayer. Factorized: h1 = relu(u[src] + v[dst]),
//   u[n] = W1[0:64]^T emb[n] + b1 + fied[n]*W1[128]
//   v[n] = W1[64:128]^T emb[n] + fied[n]*W1[129]
// fp16 storage for u,v. K1: u,v via transposed MFMA GEMM. K2: per-16-edge
// tile/wave depth-2 gather pipeline, indices prefetched one FULL iteration
// ahead (vmcnt retires in issue order; same-iteration index->gather
// dependence would force a full drain).
//
// R8 (post-mortem of R4-R7): all reordering/locality programs are net-
// negative. Model: gather service cap M~64 in-flight lines/CU, rate=M/L.
//   R0 plain: 8.25M lines @ L~380 -> 77us edge, 176 total  <- best
//   sort variants: line/latency gains < reorder cost (25-250us) every time.
// fp8 (2 lines/edge) barred: absmax already 2^-9 from fp16 storage,
// threshold unknown. => restore R0 structure exactly, plus two bounded
// deltas: b2 as MFMA C-in (proven safe R1/R2/R4), and NON-TEMPORAL hints
// on streaming-only traffic (src/dst loads, out store) so read/write-once
// streams don't evict the u/v L2 working set (57% hit rate is the asset).

#define HD 64

typedef __attribute__((ext_vector_type(8))) _Float16 half8;
typedef __attribute__((ext_vector_type(4))) _Float16 half4;
typedef __attribute__((ext_vector_type(8))) short  short8;
typedef __attribute__((ext_vector_type(8))) float  float8;
typedef __attribute__((ext_vector_type(4))) float  f32x4;

__device__ __forceinline__ half8 relu_h8(half8 x) {
    short8 b = __builtin_bit_cast(short8, x);
    short8 m = b >> 15;
    b = b & ~m;
    return __builtin_bit_cast(half8, b);
}

// ---------------- K1: u,v precompute, transposed MFMA GEMM ----------------
__global__ __launch_bounds__(256) void precompute_uv(
    const float* __restrict__ emb, const float* __restrict__ fied,
    const float* __restrict__ W1, const float* __restrict__ b1,
    _Float16* __restrict__ u, _Float16* __restrict__ v,
    int n_nodes, int ntiles)
{
    const int lane = threadIdx.x & 63;
    const int q = lane >> 4;
    const int c = lane & 15;
    const int wid = blockIdx.x * (blockDim.x >> 6) + (threadIdx.x >> 6);
    const int nw  = gridDim.x * (blockDim.x >> 6);

    half8 Au[4][2], Av[4][2];
    #pragma unroll
    for (int t = 0; t < 4; ++t)
        #pragma unroll
        for (int ks = 0; ks < 2; ++ks)
            #pragma unroll
            for (int j = 0; j < 8; ++j) {
                int k = ks * 32 + q * 8 + j;
                Au[t][ks][j] = (_Float16)W1[k * HD + t * 16 + c];
                Av[t][ks][j] = (_Float16)W1[(64 + k) * HD + t * 16 + c];
            }
    f32x4 b1q[4], wsq[4], wdq[4];
    #pragma unroll
    for (int t = 0; t < 4; ++t) {
        b1q[t] = *(const f32x4*)(b1 + t * 16 + q * 4);
        wsq[t] = *(const f32x4*)(W1 + 128 * HD + t * 16 + q * 4);
        wdq[t] = *(const f32x4*)(W1 + 129 * HD + t * 16 + q * 4);
    }

    for (int tile = wid; tile < ntiles; tile += nw) {
        const int n0 = tile * 16;
        const int n  = n0 + c;
        int na = n; if (na >= n_nodes) na = n_nodes - 1;
        const float* rp = emb + (size_t)na * HD + q * 8;
        float8 a0 = *(const float8*)rp;
        float8 a1 = *(const float8*)(rp + 32);
        half8 B0 = __builtin_convertvector(a0, half8);
        half8 B1 = __builtin_convertvector(a1, half8);

        f32x4 aU[4] = {}, aV[4] = {};
        #pragma unroll
        for (int t = 0; t < 4; ++t) {
            aU[t] = __builtin_amdgcn_mfma_f32_16x16x32_f16(Au[t][0], B0, aU[t], 0, 0, 0);
            aU[t] = __builtin_amdgcn_mfma_f32_16x16x32_f16(Au[t][1], B1, aU[t], 0, 0, 0);
            aV[t] = __builtin_amdgcn_mfma_f32_16x16x32_f16(Av[t][0], B0, aV[t], 0, 0, 0);
            aV[t] = __builtin_amdgcn_mfma_f32_16x16x32_f16(Av[t][1], B1, aV[t], 0, 0, 0);
        }

        const float fv = fied[na];
        const bool ok = (n < n_nodes);
        #pragma unroll
        for (int t = 0; t < 4; ++t) {
            half4 hu, hv;
            #pragma unroll
            for (int r = 0; r < 4; ++r) {
                hu[r] = (_Float16)(aU[t][r] + b1q[t][r] + fv * wsq[t][r]);
                hv[r] = (_Float16)(aV[t][r] + fv * wdq[t][r]);
            }
            if (ok) {
                *(half4*)(u + (size_t)n * HD + t * 16 + q * 4) = hu;
                *(half4*)(v + (size_t)n * HD + t * 16 + q * 4) = hv;
            }
        }
    }
}

// ---------------- K2: per-edge MLP (layers 2+3) ----------------
// D' = W2^T . h1^T : A = W2^T (preloaded), B = h1^T (gathered).
// D' layout: col = c = edge, row = q*4+r = feature t*16+q*4+r.
__global__ __launch_bounds__(256) void edge_mlp(
    const _Float16* __restrict__ u, const _Float16* __restrict__ v,
    const int* __restrict__ src, const int* __restrict__ dst,
    const float* __restrict__ W2, const float* __restrict__ b2,
    const float* __restrict__ W3, const float* __restrict__ b3,
    float* __restrict__ out, int E, int ntiles)
{
    const int lane = threadIdx.x & 63;
    const int q = lane >> 4;
    const int c = lane & 15;
    const int wid = blockIdx.x * (blockDim.x >> 6) + (threadIdx.x >> 6);
    const int nw  = gridDim.x * (blockDim.x >> 6);

    half8 Af[4][2];
    #pragma unroll
    for (int t = 0; t < 4; ++t)
        #pragma unroll
        for (int ks = 0; ks < 2; ++ks)
            #pragma unroll
            for (int j = 0; j < 8; ++j) {
                int k = ks * 32 + q * 8 + j;
                Af[t][ks][j] = (_Float16)W2[k * HD + t * 16 + c];
            }
    f32x4 b2q[4], w3q[4];
    #pragma unroll
    for (int t = 0; t < 4; ++t) {
        b2q[t] = *(const f32x4*)(b2 + t * 16 + q * 4);
        w3q[t] = *(const f32x4*)(W3 + t * 16 + q * 4);
    }
    const float b3v = b3[0];

    const int stride = nw * 2;
    const int base0  = wid * 2;

    // clamped edge id for a tile (always-valid loads; stores guarded)
    auto eid = [&](int tile) {
        int t = tile; if (t >= ntiles) t = ntiles - 1;
        int e = t * 16 + c; if (e >= E) e = E - 1;
        return e;
    };
    // index loads: read-once streams -> non-temporal (don't evict u/v in L2)
    auto ldi = [&](const int* p) { return __builtin_nontemporal_load(p); };
    auto issue = [&](int s, int d, half8& Ua, half8& Ub, half8& Va, half8& Vb) {
        const half8* up = (const half8*)(u + (unsigned)s * HD + q * 8);
        const half8* vp = (const half8*)(v + (unsigned)d * HD + q * 8);
        Ua = up[0]; Ub = up[4]; Va = vp[0]; Vb = vp[4];
    };
    auto compute_store = [&](int tile, half8 Ua, half8 Ub, half8 Va, half8 Vb) {
        half8 B0 = relu_h8(Ua + Va);
        half8 B1 = relu_h8(Ub + Vb);
        f32x4 acc[4];
        #pragma unroll
        for (int t = 0; t < 4; ++t) acc[t] = b2q[t];   // b2 via MFMA C-in
        #pragma unroll
        for (int t = 0; t < 4; ++t) {
            acc[t] = __builtin_amdgcn_mfma_f32_16x16x32_f16(Af[t][0], B0, acc[t], 0, 0, 0);
            acc[t] = __builtin_amdgcn_mfma_f32_16x16x32_f16(Af[t][1], B1, acc[t], 0, 0, 0);
        }
        float p = 0.f;
        #pragma unroll
        for (int t = 0; t < 4; ++t)
            #pragma unroll
            for (int r = 0; r < 4; ++r)
                p = fmaf(fmaxf(acc[t][r], 0.f), w3q[t][r], p);
        p += __shfl_xor(p, 16, 64);
        p += __shfl_xor(p, 32, 64);
        if (q == 0) {
            int e = tile * 16 + c;
            if (e < E) __builtin_nontemporal_store(p + b3v, out + e);
        }
    };

    if (base0 >= ntiles) return;

    // ---- prologue ----
    // idx stage 0: indices for tiles (base0, base0+1)
    int e0 = eid(base0), e1 = eid(base0 + 1);
    int s0 = ldi(src + e0), d0 = ldi(dst + e0);
    int s1 = ldi(src + e1), d1 = ldi(dst + e1);
    half8 U0a, U0b, V0a, V0b, U1a, U1b, V1a, V1b;
    issue(s0, d0, U0a, U0b, V0a, V0b);            // G0(base0)
    issue(s1, d1, U1a, U1b, V1a, V1b);            // G1(base0+1)
    // idx_cur: indices for tiles (base0+stride, +1) — used to REFILL next iter
    int e2 = eid(base0 + stride), e3 = eid(base0 + stride + 1);
    int sc0 = ldi(src + e2), dc0 = ldi(dst + e2);
    int sc1 = ldi(src + e3), dc1 = ldi(dst + e3);

    for (int base = base0; base < ntiles; base += stride) {
        // idx_next: indices for tiles two strides out (consumed NEXT iter)
        const int f0 = eid(base + 2 * stride), f1 = eid(base + 2 * stride + 1);
        const int sn0 = ldi(src + f0), dn0 = ldi(dst + f0);
        const int sn1 = ldi(src + f1), dn1 = ldi(dst + f1);

        // consume G0 (oldest vmem) — G1, refills, idx_next stay in flight
        compute_store(base, U0a, U0b, V0a, V0b);
        issue(sc0, dc0, U0a, U0b, V0a, V0b);      // refill G0 (idx_cur: retired long ago)

        compute_store(base + 1, U1a, U1b, V1a, V1b);
        issue(sc1, dc1, U1a, U1b, V1a, V1b);      // refill G1

        sc0 = sn0; dc0 = dn0; sc1 = sn1; dc1 = dn1;   // rotate idx pipeline
    }
}

extern "C" void kernel_launch(void* const* d_in, const int* in_sizes, int n_in,
                              void* d_out, int out_size, void* d_ws, size_t ws_size,
                              hipStream_t stream) {
    const float* emb  = (const float*)d_in[0];
    const float* fied = (const float*)d_in[1];
    const float* W1   = (const float*)d_in[2];
    const float* b1   = (const float*)d_in[3];
    const float* W2   = (const float*)d_in[4];
    const float* b2   = (const float*)d_in[5];
    const float* W3   = (const float*)d_in[6];
    const float* b3   = (const float*)d_in[7];
    const int*   eidx = (const int*)d_in[8];

    const int n_nodes = in_sizes[1];
    const int E       = in_sizes[8] / 2;
    const int* srcp = eidx;
    const int* dstp = eidx + E;

    _Float16* u = (_Float16*)d_ws;                 // n_nodes*64 fp16
    _Float16* v = u + (size_t)n_nodes * HD;        // n_nodes*64 fp16

    const int ntilesN = (n_nodes + 15) / 16;
    precompute_uv<<<1024, 256, 0, stream>>>(emb, fied, W1, b1, u, v,
                                            n_nodes, ntilesN);

    const int ntilesE = (E + 15) / 16;
    edge_mlp<<<2048, 256, 0, stream>>>(u, v, srcp, dstp, W2, b2, W3, b3,
                                       (float*)d_out, E, ntilesE);
}